// Round 1
// baseline (2990.698 us; speedup 1.0000x reference)
//
#include <hip/hip_runtime.h>
#include <math.h>

#define N_USERS 2500
#define N_ITEMS 3000
#define N_ENT   2500
#define NTOT    8000
#define D       128
#define NEDGE   256000

// ---------------------------------------------------------------------------
// Generic 4-rows-per-block linear: out[r][j] = act(sum_k A[r][k]*ks[k]*W[k][j] + b[j])
// block = 128 threads (j = column), grid.x = M/4.
// mode: 0 = none, 1 = relu, 2 = multiply-by-2 (for the collapsed cross-modal sum)
// ---------------------------------------------------------------------------
__global__ void k_lin4(const float* __restrict__ A, const float* __restrict__ W,
                       const float* __restrict__ b, const float* __restrict__ ks,
                       float* __restrict__ out, int K, int mode) {
  const int r0 = blockIdx.x * 4;
  const int j  = threadIdx.x;
  const float* __restrict__ a0 = A + (size_t)r0 * K;
  const float* __restrict__ a1 = a0 + K;
  const float* __restrict__ a2 = a1 + K;
  const float* __restrict__ a3 = a2 + K;
  float c0 = 0.f, c1 = 0.f, c2 = 0.f, c3 = 0.f;
  if (ks) {
    for (int k = 0; k < K; ++k) {
      const float w = W[(size_t)k * D + j];
      const float s = ks[k];
      c0 = fmaf(a0[k] * s, w, c0);
      c1 = fmaf(a1[k] * s, w, c1);
      c2 = fmaf(a2[k] * s, w, c2);
      c3 = fmaf(a3[k] * s, w, c3);
    }
  } else {
    for (int k = 0; k < K; ++k) {
      const float w = W[(size_t)k * D + j];
      c0 = fmaf(a0[k], w, c0);
      c1 = fmaf(a1[k], w, c1);
      c2 = fmaf(a2[k], w, c2);
      c3 = fmaf(a3[k], w, c3);
    }
  }
  const float bj = b[j];
  c0 += bj; c1 += bj; c2 += bj; c3 += bj;
  if (mode == 1) {
    c0 = fmaxf(c0, 0.f); c1 = fmaxf(c1, 0.f); c2 = fmaxf(c2, 0.f); c3 = fmaxf(c3, 0.f);
  } else if (mode == 2) {
    c0 *= 2.f; c1 *= 2.f; c2 *= 2.f; c3 *= 2.f;
  }
  float* __restrict__ o = out + (size_t)r0 * D + j;
  o[0] = c0; o[D] = c1; o[2 * D] = c2; o[3 * D] = c3;
}

// ---------------------------------------------------------------------------
// Gated fusion: g = sigmoid(sigmoid([base|mm] @ gw + gb) * 2);
// out = g*base + (1-g)*mm + 0.1*base     (writes straight into the emb buffer)
// block = 128 (j), grid.x = rows
// ---------------------------------------------------------------------------
__global__ void k_gatefuse(const float* __restrict__ base, const float* __restrict__ mm,
                           const float* __restrict__ gw, const float* __restrict__ gb,
                           float* __restrict__ embout) {
  const int r = blockIdx.x;
  const int j = threadIdx.x;
  const float* __restrict__ b0 = base + (size_t)r * D;
  const float* __restrict__ m0 = mm + (size_t)r * D;
  float acc = 0.f;
  for (int k = 0; k < D; ++k) acc = fmaf(b0[k], gw[(size_t)k * D + j], acc);
  for (int k = 0; k < D; ++k) acc = fmaf(m0[k], gw[(size_t)(D + k) * D + j], acc);
  acc += gb[j];
  const float s1 = 1.f / (1.f + expf(-acc));
  const float g  = 1.f / (1.f + expf(-(s1 * 2.f)));
  const float bv = b0[j], mv = m0[j];
  embout[(size_t)r * D + j] = g * bv + (1.f - g) * mv + 0.1f * bv;
}

// rel_mean[j] = mean over 32 relations
__global__ void k_relmean(const float* __restrict__ rel, float* __restrict__ out) {
  const int j = threadIdx.x;
  float s = 0.f;
  for (int i = 0; i < 32; ++i) s += rel[i * D + j];
  out[j] = s * (1.f / 32.f);
}

__global__ void k_copy(const float* __restrict__ src, float* __restrict__ dst, int n) {
  const int t = blockIdx.x * blockDim.x + threadIdx.x;
  if (t < n) dst[t] = src[t];
}

// ---------------------------------------------------------------------------
// side[row] += data * e[col]  via f32 atomics. one thread per (edge, d)
// ---------------------------------------------------------------------------
__global__ void k_spmm(const float* __restrict__ dat, const int* __restrict__ rw,
                       const int* __restrict__ cl, const float* __restrict__ e,
                       float* __restrict__ side) {
  const long long t = (long long)blockIdx.x * blockDim.x + threadIdx.x;
  if (t >= (long long)NEDGE * D) return;
  const int ei = (int)(t >> 7);
  const int d  = (int)(t & 127);
  const float v = dat[ei] * e[(size_t)cl[ei] * D + d];
  atomicAdd(side + (size_t)rw[ei] * D + d, v);
}

// ---------------------------------------------------------------------------
// Fused scores + top-16 + softmax + gather-aggregate + relu.
// Block = 256 (4 waves), 16 rows/block (4 rows/wave). kn staged in LDS tiles
// of 64 m-rows (row stride 129 words -> only 2-way bank aliasing, free).
// Top-16 per row lives distributed in lanes 0..15 (val,idx) with a running
// threshold; insertion via ballot + 16-lane shfl argmin. Ties evict the
// larger index, matching jax.lax.top_k's lower-index preference.
// ---------------------------------------------------------------------------
__device__ __forceinline__ void topk_insert_ballot(float s, int m0, int lane,
                                                   float& slotv, int& sloti, float& thr) {
  unsigned long long ball = __ballot(s > thr);
  while (ball) {
    const int src = __ffsll(ball) - 1;
    ball &= ball - 1;
    const float sv = __shfl(s, src);
    const int   sm = m0 + src;
    // argmin over the 16 slot lanes (value asc, tie -> larger stored idx loses)
    float mv = (lane < 16) ? slotv : 3.0e38f;
    int   mi = (lane < 16) ? sloti : 0x7fffffff;
    int   ml = lane;
#pragma unroll
    for (int d = 1; d < 16; d <<= 1) {
      const float ov = __shfl_xor(mv, d);
      const int   oi = __shfl_xor(mi, d);
      const int   ol = __shfl_xor(ml, d);
      if (ov < mv || (ov == mv && oi > mi)) { mv = ov; mi = oi; ml = ol; }
    }
    const float minv = __shfl(mv, 0);
    const int   minl = __shfl(ml, 0);
    if (sv > minv) {                       // wave-uniform
      if (lane == minl) { slotv = sv; sloti = sm; }
      float t = (lane < 16) ? slotv : 3.0e38f;
#pragma unroll
      for (int d = 1; d < 16; d <<= 1) t = fminf(t, __shfl_xor(t, d));
      thr = __shfl(t, 0);
    }
  }
}

__device__ __forceinline__ void softmax_agg_store(float slotv, int sloti, int lane,
                                                  const float* __restrict__ vn,
                                                  float* __restrict__ eout, int r) {
  float v = (lane < 16) ? slotv : -3.0e38f;
  float mx = v;
#pragma unroll
  for (int d = 1; d < 16; d <<= 1) mx = fmaxf(mx, __shfl_xor(mx, d));
  const float e = (lane < 16) ? expf(v - mx) : 0.f;
  float s = e;
#pragma unroll
  for (int d = 1; d < 16; d <<= 1) s += __shfl_xor(s, d);
  const float w = e / s;                   // valid on lanes < 16
  float acc0 = 0.f, acc1 = 0.f;
#pragma unroll
  for (int j = 0; j < 16; ++j) {
    const float wj = __shfl(w, j);
    const int   tj = __shfl(sloti, j);
    const float* __restrict__ vr = vn + (size_t)tj * D;
    acc0 = fmaf(wj, vr[lane], acc0);
    acc1 = fmaf(wj, vr[64 + lane], acc1);
  }
  eout[(size_t)r * D + lane]      = fmaxf(acc0, 0.f);
  eout[(size_t)r * D + 64 + lane] = fmaxf(acc1, 0.f);
}

__global__ __launch_bounds__(256) void k_scores_topk(
    const float* __restrict__ qn, const float* __restrict__ kn,
    const float* __restrict__ vn, float* __restrict__ eout) {
  __shared__ float knS[64 * 129];
  const int tid  = threadIdx.x;
  const int lane = tid & 63;
  const int wave = tid >> 6;
  const int rbase = __builtin_amdgcn_readfirstlane((int)(blockIdx.x * 16 + wave * 4));
  const float inv = 0.088388347648318447f;  // 1/sqrt(128)

  float slotv[4]; int sloti[4]; float thr[4];
#pragma unroll
  for (int i = 0; i < 4; ++i) { slotv[i] = -3.0e38f; sloti[i] = 0x7fffffff; thr[i] = -3.0e38f; }

  const float* __restrict__ q0 = qn + (size_t)rbase * D;
  const float* __restrict__ q1 = q0 + D;
  const float* __restrict__ q2 = q1 + D;
  const float* __restrict__ q3 = q2 + D;

  for (int mt = 0; mt < NTOT; mt += 64) {
    __syncthreads();
    for (int e = tid; e < 64 * 128; e += 256) {
      const int m = e >> 7, k = e & 127;
      knS[m * 129 + k] = kn[(size_t)(mt + m) * D + k];
    }
    __syncthreads();
    const float* __restrict__ kl = knS + lane * 129;
    float a0 = 0.f, a1 = 0.f, a2 = 0.f, a3 = 0.f;
#pragma unroll 8
    for (int k = 0; k < 128; ++k) {
      const float kv = kl[k];
      a0 = fmaf(q0[k], kv, a0);
      a1 = fmaf(q1[k], kv, a1);
      a2 = fmaf(q2[k], kv, a2);
      a3 = fmaf(q3[k], kv, a3);
    }
    topk_insert_ballot(a0 * inv, mt, lane, slotv[0], sloti[0], thr[0]);
    topk_insert_ballot(a1 * inv, mt, lane, slotv[1], sloti[1], thr[1]);
    topk_insert_ballot(a2 * inv, mt, lane, slotv[2], sloti[2], thr[2]);
    topk_insert_ballot(a3 * inv, mt, lane, slotv[3], sloti[3], thr[3]);
  }
  softmax_agg_store(slotv[0], sloti[0], lane, vn, eout, rbase + 0);
  softmax_agg_store(slotv[1], sloti[1], lane, vn, eout, rbase + 1);
  softmax_agg_store(slotv[2], sloti[2], lane, vn, eout, rbase + 2);
  softmax_agg_store(slotv[3], sloti[3], lane, vn, eout, rbase + 3);
}

// ---------------------------------------------------------------------------
// final = [e0|e1|e2] @ la_w + la_b, then row-L2-normalize; rows 0..5499 only.
// Users -> d_out[0..], items -> d_out[N_USERS*D..]
// ---------------------------------------------------------------------------
__global__ void k_final_norm(const float* __restrict__ e0, const float* __restrict__ e1,
                             const float* __restrict__ e2, const float* __restrict__ law,
                             const float* __restrict__ lab, float* __restrict__ out) {
  __shared__ float red[128];
  const int r = blockIdx.x;
  const int j = threadIdx.x;
  const float* __restrict__ a0 = e0 + (size_t)r * D;
  const float* __restrict__ a1 = e1 + (size_t)r * D;
  const float* __restrict__ a2 = e2 + (size_t)r * D;
  float acc = lab[j];
  for (int k = 0; k < D; ++k) acc = fmaf(a0[k], law[(size_t)k * D + j], acc);
  for (int k = 0; k < D; ++k) acc = fmaf(a1[k], law[(size_t)(D + k) * D + j], acc);
  for (int k = 0; k < D; ++k) acc = fmaf(a2[k], law[(size_t)(2 * D + k) * D + j], acc);
  red[j] = acc * acc;
  __syncthreads();
  for (int st = 64; st > 0; st >>= 1) {
    if (j < st) red[j] += red[j + st];
    __syncthreads();
  }
  const float nrm = fmaxf(sqrtf(red[0]), 1e-12f);
  const float o = acc / nrm;
  if (r < N_USERS) out[(size_t)r * D + j] = o;
  else             out[(size_t)N_USERS * D + (size_t)(r - N_USERS) * D + j] = o;
}

// ---------------------------------------------------------------------------
extern "C" void kernel_launch(void* const* d_in, const int* in_sizes, int n_in,
                              void* d_out, int out_size, void* d_ws, size_t ws_size,
                              hipStream_t stream) {
  const float* user_w = (const float*)d_in[0];
  const float* item_w = (const float*)d_in[1];
  const float* ent_w  = (const float*)d_in[2];
  const float* rel_w  = (const float*)d_in[3];
  const float* mfeat  = (const float*)d_in[4];
  const float* ufeat  = (const float*)d_in[5];
  const float* me_w1  = (const float*)d_in[6];
  const float* me_b1  = (const float*)d_in[7];
  const float* me_w2  = (const float*)d_in[8];
  const float* me_b2  = (const float*)d_in[9];
  const float* ue_w1  = (const float*)d_in[10];
  const float* ue_b1  = (const float*)d_in[11];
  const float* ue_w2  = (const float*)d_in[12];
  const float* ue_b2  = (const float*)d_in[13];
  const float* cm_vw  = (const float*)d_in[18];
  const float* cm_vb  = (const float*)d_in[19];
  const float* cm_ow  = (const float*)d_in[20];
  const float* cm_ob  = (const float*)d_in[21];
  const float* mg_w   = (const float*)d_in[22];
  const float* mg_b   = (const float*)d_in[23];
  const float* ug_w   = (const float*)d_in[24];
  const float* ug_b   = (const float*)d_in[25];
  const float* gnn_qw = (const float*)d_in[26];
  const float* gnn_qb = (const float*)d_in[27];
  const float* gnn_kw = (const float*)d_in[28];
  const float* gnn_kb = (const float*)d_in[29];
  const float* gnn_vw = (const float*)d_in[30];
  const float* gnn_vb = (const float*)d_in[31];
  const float* la_w   = (const float*)d_in[32];
  const float* la_b   = (const float*)d_in[33];
  const float* adj_d  = (const float*)d_in[34];
  const int*   adj_r  = (const int*)d_in[35];
  const int*   adj_c  = (const int*)d_in[36];
  float* out = (float*)d_out;
  float* ws  = (float*)d_ws;

  // ---- workspace layout (floats) ----
  size_t off = 0;
  float* mm_item = ws + off; off += (size_t)N_ITEMS * D;   // 384000
  float* mm_user = ws + off; off += (size_t)N_USERS * D;   // 320000
  float* enc     = ws + off; off += (size_t)N_ITEMS * D;   // 384000
  float* tmp     = ws + off; off += (size_t)N_ITEMS * D;   // 384000 (hid_item/hid_user/v)
  float* emb0    = ws + off; off += (size_t)NTOT * D;
  float* emb1    = ws + off; off += (size_t)NTOT * D;
  float* emb2    = ws + off; off += (size_t)NTOT * D;
  float* side    = ws + off; off += (size_t)NTOT * D;
  float* qn      = ws + off; off += (size_t)NTOT * D;
  float* kn      = ws + off; off += (size_t)NTOT * D;
  float* vn      = ws + off; off += (size_t)NTOT * D;
  float* relmean = ws + off; off += D;

  // ---- modality encoders ----
  k_lin4<<<N_ITEMS / 4, D, 0, stream>>>(mfeat, me_w1, me_b1, nullptr, tmp, 768, 1);
  k_lin4<<<N_ITEMS / 4, D, 0, stream>>>(tmp, me_w2, me_b2, nullptr, enc, 128, 1);
  k_lin4<<<N_USERS / 4, D, 0, stream>>>(ufeat, ue_w1, ue_b1, nullptr, tmp, 512, 1);
  k_lin4<<<N_USERS / 4, D, 0, stream>>>(tmp, ue_w2, ue_b2, nullptr, mm_user, 128, 1);
  // ---- collapsed cross-modal attention: mm_item = 2*((enc@vw+vb)@ow+ob) ----
  k_lin4<<<N_ITEMS / 4, D, 0, stream>>>(enc, cm_vw, cm_vb, nullptr, tmp, 128, 0);
  k_lin4<<<N_ITEMS / 4, D, 0, stream>>>(tmp, cm_ow, cm_ob, nullptr, mm_item, 128, 2);
  // ---- gated fusion -> emb0 ----
  k_gatefuse<<<N_ITEMS, D, 0, stream>>>(item_w, mm_item, mg_w, mg_b, emb0 + (size_t)N_USERS * D);
  k_gatefuse<<<N_USERS, D, 0, stream>>>(user_w, mm_user, ug_w, ug_b, emb0);
  k_copy<<<(N_ENT * D + 255) / 256, 256, 0, stream>>>(ent_w, emb0 + (size_t)(N_USERS + N_ITEMS) * D, N_ENT * D);
  k_relmean<<<1, D, 0, stream>>>(rel_w, relmean);

  // ---- GNN layers ----
  const long long spthreads = (long long)NEDGE * D;
  const int spgrid = (int)((spthreads + 255) / 256);
  const float* eml[3] = {emb0, emb1, emb2};
  for (int l = 0; l < 2; ++l) {
    const float* e = eml[l];
    float* enext   = (float*)eml[l + 1];
    hipMemsetAsync(side, 0, (size_t)NTOT * D * sizeof(float), stream);
    k_spmm<<<spgrid, 256, 0, stream>>>(adj_d, adj_r, adj_c, e, side);
    k_lin4<<<NTOT / 4, D, 0, stream>>>(e,    gnn_qw + (size_t)l * D * D, gnn_qb + (size_t)l * D, nullptr, qn, 128, 0);
    k_lin4<<<NTOT / 4, D, 0, stream>>>(side, gnn_kw + (size_t)l * D * D, gnn_kb + (size_t)l * D, relmean, kn, 128, 0);
    k_lin4<<<NTOT / 4, D, 0, stream>>>(side, gnn_vw + (size_t)l * D * D, gnn_vb + (size_t)l * D, nullptr, vn, 128, 0);
    k_scores_topk<<<NTOT / 16, 256, 0, stream>>>(qn, kn, vn, enext);
  }

  // ---- layer aggregation + normalize -> d_out ----
  k_final_norm<<<N_USERS + N_ITEMS, D, 0, stream>>>(emb0, emb1, emb2, la_w, la_b, out);
  // ---- passthrough outputs ----
  k_copy<<<(N_ITEMS * D + 255) / 256, 256, 0, stream>>>(item_w, out + (size_t)(N_USERS + N_ITEMS) * D, N_ITEMS * D);
  k_copy<<<(N_ITEMS * D + 255) / 256, 256, 0, stream>>>(mm_item, out + (size_t)(N_USERS + 2 * N_ITEMS + N_ITEMS) * D - (size_t)N_ITEMS * D, N_ITEMS * D);
}